// Round 5
// baseline (357.971 us; speedup 1.0000x reference)
//
#include <hip/hip_runtime.h>
#include <hip/hip_bf16.h>
#include <stdint.h>

typedef __attribute__((ext_vector_type(4))) float f32x4;
typedef __attribute__((ext_vector_type(16))) float f32x16;
typedef __attribute__((ext_vector_type(2))) float f32x2;
typedef __attribute__((ext_vector_type(8))) short s16x8;
typedef __attribute__((ext_vector_type(4))) unsigned short u16x4;

__device__ __forceinline__ unsigned short f2bf(float f) {
  union { float f; uint32_t u; } v; v.f = f;
  uint32_t r = v.u + 0x7fffu + ((v.u >> 16) & 1u);
  return (unsigned short)(r >> 16);
}

__device__ __forceinline__ void load_lds16(const void* g, void* l) {
  __builtin_amdgcn_global_load_lds(
      (const __attribute__((address_space(1))) void*)g,
      (__attribute__((address_space(3))) void*)l, 16, 0, 0);
}

#define MFMA16(a, b, c) __builtin_amdgcn_mfma_f32_16x16x32_bf16((a), (b), (c), 0, 0, 0)
#define MFMA32(a, b, c) __builtin_amdgcn_mfma_f32_32x32x16_bf16((a), (b), (c), 0, 0, 0)

// ---------------- fp32 -> bf16 convert (vectorized) ----------------
__global__ void k_cvt(const float* __restrict__ in, unsigned short* __restrict__ out, int n4) {
  int i = blockIdx.x * blockDim.x + threadIdx.x;
  int stride = gridDim.x * blockDim.x;
  for (; i < n4; i += stride) {
    f32x4 v = ((const f32x4*)in)[i];
    u16x4 o;
    o[0] = f2bf(v[0]); o[1] = f2bf(v[1]); o[2] = f2bf(v[2]); o[3] = f2bf(v[3]);
    ((u16x4*)out)[i] = o;
  }
}

// ------- rope -> (cos,sin) tables; q-table pre-scaled by 0.125*log2(e) -------
__global__ __launch_bounds__(256) void k_rope_tab(const float* __restrict__ rope,
    float* __restrict__ tq, float* __restrict__ tk) {
  int i = blockIdx.x * blockDim.x + threadIdx.x;   // over 2048*64
  float p = rope[i];
  float sn, cs; __sincosf(p, &sn, &cs);
  const float a1 = 0.18033688011112042f;           // 0.125 * log2(e)
  f32x2 a = {cs * a1, sn * a1};
  f32x2 b = {cs, sn};
  ((f32x2*)tq)[i] = a;
  ((f32x2*)tk)[i] = b;
}

// ---------------- fp32 [K][N] -> bf16 [N][K] transpose ----------------
__global__ __launch_bounds__(256) void k_transpose(const float* __restrict__ in,
    unsigned short* __restrict__ out, int K, int N) {
  __shared__ float t[32][33];
  const int tx = threadIdx.x, ty = threadIdx.y;
  const int n0 = blockIdx.x * 32, k0 = blockIdx.y * 32;
#pragma unroll
  for (int i = 0; i < 32; i += 8) t[ty + i][tx] = in[(size_t)(k0 + ty + i) * N + n0 + tx];
  __syncthreads();
#pragma unroll
  for (int i = 0; i < 32; i += 8) out[(size_t)(n0 + ty + i) * K + k0 + tx] = f2bf(t[tx][ty + i]);
}

// ============ pipelined GEMM: BM=256, BN=128, BK=32, 512 thr, 3-buf LDS ============
// MODE 0: qkv projection with fused RoPE / V-transpose epilogue (N=3072)
// MODE 1: output projection + bias, fp32 out (N=1024)
// LDS per tile: A [4 kchunk][256 row][16B] = 16 KB, B [4 kchunk][128 row][16B] = 8 KB.
// 3 rotating buffers (compute t from buf0, t+1 in buf1, stage t+2 into buf2);
// counted vmcnt(3) BEFORE each raw barrier keeps 3 loads/wave in flight (T3+T4).
template<int MODE>
__global__ __launch_bounds__(512, 4) void k_gemm8(
    const unsigned short* __restrict__ A, const unsigned short* __restrict__ Bt,
    const float* __restrict__ tq, const float* __restrict__ tk,
    unsigned short* __restrict__ qw, unsigned short* __restrict__ kw,
    unsigned short* __restrict__ vt,
    const float* __restrict__ bo, float* __restrict__ outf) {
  __shared__ char lds[73728];
  constexpr int NTN = (MODE == 0) ? 24 : 8;

  // XCD-aware swizzle (grid % 8 == 0 -> simple bijective form)
  const int nwg = gridDim.x, cpx = nwg >> 3, bid = blockIdx.x;
  const int swz = (bid & 7) * cpx + (bid >> 3);
  const int tm = swz / NTN, tn = swz % NTN;

  const int tid = threadIdx.x, l = tid & 63, w = tid >> 6;
  const int wm = w >> 1, wn = w & 1;
  const int lg = l >> 4, lr = l & 15;

  // rotating LDS slot byte offsets (uniform -> SGPR)
  unsigned a0 = 0u, a1 = 16384u, a2 = 32768u;
  unsigned b0 = 49152u, b1 = 57344u, b2 = 65536u;

  // staging source pointers (this thread's fixed slice; advance 32 elems/tile)
  const unsigned short* Ap = A + (size_t)(tm * 256 + (tid & 255)) * 1024 + (tid >> 8) * 8;
  const unsigned short* Bp = Bt + (size_t)(tn * 128 + (tid & 127)) * 1024 + (tid >> 7) * 8;

  const unsigned aoff = lg * 4096 + (wm * 64 + lr) * 16;   // + mi*256
  const unsigned boff = lg * 2048 + (wn * 64 + lr) * 16;   // + ni*256

  auto STAGE = [&](unsigned sa, unsigned sb) {
    load_lds16(Ap, lds + sa + tid * 16);
    load_lds16(Ap + 16, lds + sa + 8192 + tid * 16);
    load_lds16(Bp, lds + sb + tid * 16);
    Ap += 32; Bp += 32;
  };

  f32x4 acc[4][4] = {};

  STAGE(a0, b0);          // tile 0
  STAGE(a1, b1);          // tile 1

  for (int t = 0; t < 32; ++t) {
    // certify tile t resident for ALL waves: counted wait, then raw barrier
    if (t <= 30) asm volatile("s_waitcnt vmcnt(3)" ::: "memory");
    else         asm volatile("s_waitcnt vmcnt(0)" ::: "memory");
    __builtin_amdgcn_s_barrier();

    s16x8 bf[4], af[4];
#pragma unroll
    for (int ni = 0; ni < 4; ++ni)
      bf[ni] = *(const s16x8*)(lds + b0 + boff + ni * 256);
#pragma unroll
    for (int mi = 0; mi < 4; ++mi)
      af[mi] = *(const s16x8*)(lds + a0 + aoff + mi * 256);

    if (t < 30) STAGE(a2, b2);          // prefetch tile t+2 (3 loads stay in flight)

    __builtin_amdgcn_s_setprio(1);
#pragma unroll
    for (int mi = 0; mi < 4; ++mi)
#pragma unroll
      for (int ni = 0; ni < 4; ++ni)
        acc[mi][ni] = MFMA16(af[mi], bf[ni], acc[mi][ni]);
    __builtin_amdgcn_s_setprio(0);

    unsigned ra = a0; a0 = a1; a1 = a2; a2 = ra;
    unsigned rb = b0; b0 = b1; b1 = b2; b2 = rb;
  }

  const int c0 = tn * 128 + wn * 64;
  const int r0 = tm * 256 + wm * 64;

  if constexpr (MODE == 0) {
    const int tensor = c0 >> 10;
    const int h = (c0 & 1023) >> 6;
    if (tensor < 2) {
      unsigned short* dst = tensor == 0 ? qw : kw;
      const float* tbl = tensor == 0 ? tq : tk;
#pragma unroll
      for (int mi = 0; mi < 4; ++mi) {
#pragma unroll
        for (int reg = 0; reg < 4; ++reg) {
          int m = r0 + mi * 16 + lg * 4 + reg;
          int b = m >> 11, n = m & 2047;
          size_t base = ((size_t)(b * 16 + h) * 2048 + n) * 64;
          const float* tb2 = tbl + (size_t)n * 128;
#pragma unroll
          for (int ni = 0; ni < 4; ++ni) {
            int d = ni * 16 + lr;
            f32x2 cssn = *(const f32x2*)(tb2 + 2 * d);
            float val = acc[mi][ni][reg];
            float partner = acc[mi][ni ^ 2][reg];     // element at d^32, same lane
            dst[base + d] = f2bf(val * cssn[0] + (d < 32 ? -partner : partner) * cssn[1]);
          }
        }
      }
    } else {
      // v: write transposed [bh][d][n], 8-byte packed (4 consecutive n per lane)
#pragma unroll
      for (int mi = 0; mi < 4; ++mi) {
        int m0 = r0 + mi * 16 + lg * 4;
        int b = m0 >> 11, n0 = m0 & 2047;
#pragma unroll
        for (int ni = 0; ni < 4; ++ni) {
          int d = ni * 16 + lr;
          u16x4 vv;
#pragma unroll
          for (int reg = 0; reg < 4; ++reg) vv[reg] = f2bf(acc[mi][ni][reg]);
          *(u16x4*)(vt + ((size_t)(b * 16 + h) * 64 + d) * 2048 + n0) = vv;
        }
      }
    }
  } else {
#pragma unroll
    for (int mi = 0; mi < 4; ++mi)
#pragma unroll
      for (int reg = 0; reg < 4; ++reg) {
        int m = r0 + mi * 16 + lg * 4 + reg;
#pragma unroll
        for (int ni = 0; ni < 4; ++ni) {
          int c = c0 + ni * 16 + lr;
          outf[(size_t)m * 1024 + c] = acc[mi][ni][reg] + bo[c];
        }
      }
  }
}

// -------- flash attention: 4 waves x 32 q-rows, KV=64, 32x32 MFMA, in-reg P --------
__global__ __launch_bounds__(256, 4) void k_attn(const unsigned short* __restrict__ qw,
    const unsigned short* __restrict__ kw, const unsigned short* __restrict__ vt,
    unsigned short* __restrict__ aout) {
  __shared__ alignas(16) unsigned short Kb[2][4096];
  __shared__ alignas(16) unsigned short Vb[2][4096];
  const int tid = threadIdx.x, l = tid & 63, w = tid >> 6;
  const int ql = l & 31, hi = l >> 5;
  const int bh = blockIdx.y;
  const int qb = blockIdx.x * 128 + w * 32;
  const size_t hbase = (size_t)bh * 2048 * 64;

  s16x8 qf[4];
#pragma unroll
  for (int kt = 0; kt < 4; ++kt)
    qf[kt] = *(const s16x8*)(qw + hbase + (size_t)(qb + ql) * 64 + kt * 16 + hi * 8);

  f32x16 o0 = {}, o1 = {};
  float lsum = 0.f;

  auto STAGE = [&](int kv0, int buf) {
#pragma unroll
    for (int i = 0; i < 2; ++i) {
      int off = i * 4096 + tid * 16;
      int blk = off >> 10, row = (off >> 4) & 63;
      load_lds16(kw + hbase + (size_t)(kv0 + row) * 64 + blk * 8, (char*)Kb[buf] + off);
      load_lds16(vt + hbase + (size_t)row * 2048 + kv0 + blk * 8, (char*)Vb[buf] + off);
    }
  };

  auto COMPUTE = [&](const unsigned short* Kc, const unsigned short* Vc) {
    f32x16 s0 = {}, s1 = {};
    const char* Kp = (const char*)Kc + hi * 1024 + ql * 16;
    __builtin_amdgcn_s_setprio(1);
#pragma unroll
    for (int kt = 0; kt < 4; ++kt) {
      s16x8 kf0 = *(const s16x8*)(Kp + kt * 2048);
      s16x8 kf1 = *(const s16x8*)(Kp + kt * 2048 + 512);
      s0 = MFMA32(kf0, qf[kt], s0);
      s1 = MFMA32(kf1, qf[kt], s1);
    }
    __builtin_amdgcn_s_setprio(0);

    float ls = 0.f;
#pragma unroll
    for (int r = 0; r < 16; ++r) { s0[r] = exp2f(s0[r]); ls += s0[r]; }
#pragma unroll
    for (int r = 0; r < 16; ++r) { s1[r] = exp2f(s1[r]); ls += s1[r]; }
    lsum += ls + __shfl_xor(ls, 32);

    uint32_t W0[8], W1[8];
#pragma unroll
    for (int b = 0; b < 4; ++b)
#pragma unroll
      for (int h2 = 0; h2 < 2; ++h2) {
        asm("v_cvt_pk_bf16_f32 %0, %1, %2" : "=v"(W0[b * 2 + h2])
            : "v"(s0[4 * b + 2 * h2]), "v"(s0[4 * b + 2 * h2 + 1]));
        asm("v_cvt_pk_bf16_f32 %0, %1, %2" : "=v"(W1[b * 2 + h2])
            : "v"(s1[4 * b + 2 * h2]), "v"(s1[4 * b + 2 * h2 + 1]));
      }
    s16x8 pa[4];
#pragma unroll
    for (int kt = 0; kt < 4; ++kt) {
      uint32_t* Wm = (kt >> 1) ? W1 : W0;
      int k = kt & 1;
      uint32_t x0 = Wm[4 * k + 0], y0 = Wm[4 * k + 2];
      uint32_t x1 = Wm[4 * k + 1], y1 = Wm[4 * k + 3];
      asm("v_permlane32_swap_b32 %0, %1" : "+v"(x0), "+v"(y0));
      asm("v_permlane32_swap_b32 %0, %1" : "+v"(x1), "+v"(y1));
      union { uint32_t u[4]; s16x8 v; } pk;
      pk.u[0] = x0; pk.u[1] = x1; pk.u[2] = y0; pk.u[3] = y1;
      pa[kt] = pk.v;
    }

    const char* Vp = (const char*)Vc + hi * 1024 + ql * 16;
    __builtin_amdgcn_s_setprio(1);
#pragma unroll
    for (int kt = 0; kt < 4; ++kt) {
      s16x8 vf0 = *(const s16x8*)(Vp + kt * 2048);
      s16x8 vf1 = *(const s16x8*)(Vp + kt * 2048 + 512);
      o0 = MFMA32(pa[kt], vf0, o0);
      o1 = MFMA32(pa[kt], vf1, o1);
    }
    __builtin_amdgcn_s_setprio(0);
  };

  STAGE(0, 0);
  __syncthreads();
  for (int t = 0; t < 32; t += 2) {
    if (t + 1 < 32) STAGE((t + 1) * 64, 1);
    COMPUTE(Kb[0], Vb[0]);
    __syncthreads();
    if (t + 2 < 32) STAGE((t + 2) * 64, 0);
    COMPUTE(Kb[1], Vb[1]);
    __syncthreads();
  }

  const int b = bh >> 4, h = bh & 15;
  float inv = 1.f / lsum;
#pragma unroll
  for (int r = 0; r < 16; ++r) {
    int qloc = (r & 3) + 8 * (r >> 2) + 4 * hi;
    float ir = __shfl(inv, qloc);
    size_t ob = ((size_t)(b * 2048 + qb + qloc) * 16 + h) * 64;
    aout[ob + ql] = f2bf(o0[r] * ir);
    aout[ob + 32 + ql] = f2bf(o1[r] * ir);
  }
}

extern "C" void kernel_launch(void* const* d_in, const int* in_sizes, int n_in,
                              void* d_out, int out_size, void* d_ws, size_t ws_size,
                              hipStream_t stream) {
  const float* x    = (const float*)d_in[0];
  const float* rope = (const float*)d_in[1];
  const float* Wq   = (const float*)d_in[2];
  const float* Wkv  = (const float*)d_in[3];
  const float* Wo   = (const float*)d_in[4];
  const float* bo   = (const float*)d_in[5];
  float* out = (float*)d_out;

  unsigned short* ws  = (unsigned short*)d_ws;
  unsigned short* xb  = ws;                               // 8192*1024
  unsigned short* wt  = xb + 8192 * 1024;                 // 3072*1024 (q|k|v cols, N-major)
  unsigned short* wot = wt + 3072 * 1024;                 // 1024*1024
  unsigned short* qws = wot + 1024 * 1024;                // 64*2048*64
  unsigned short* kws = qws + 64 * 2048 * 64;
  unsigned short* vtw = kws + 64 * 2048 * 64;             // v TRANSPOSED [bh][64][2048]
  float* tq = (float*)(vtw + 64 * 2048 * 64);             // 2048*64*2 f32 (scaled cos,sin)
  float* tk = tq + 2048 * 64 * 2;                         // 2048*64*2 f32
  unsigned short* aws = xb;                               // reuse x buffer for attn out

  k_cvt<<<1024, 256, 0, stream>>>(x, xb, 8192 * 1024 / 4);
  k_rope_tab<<<512, 256, 0, stream>>>(rope, tq, tk);
  dim3 tb(32, 8);
  k_transpose<<<dim3(32, 32), tb, 0, stream>>>(Wq, wt, 1024, 1024);
  k_transpose<<<dim3(64, 32), tb, 0, stream>>>(Wkv, wt + 1024 * 1024, 1024, 2048);
  k_transpose<<<dim3(32, 32), tb, 0, stream>>>(Wo, wot, 1024, 1024);

  k_gemm8<0><<<768, 512, 0, stream>>>(xb, wt, tq, tk, qws, kws, vtw, nullptr, nullptr);
  k_attn<<<dim3(16, 64), 256, 0, stream>>>(qws, kws, vtw, aws);
  k_gemm8<1><<<256, 512, 0, stream>>>(aws, wot, nullptr, nullptr, nullptr, nullptr, nullptr, bo, out);
}